// Round 3
// baseline (70.542 us; speedup 1.0000x reference)
//
#include <hip/hip_runtime.h>

// Problem constants: x:(B,G) f32, WQ/WK/WV:(H,G,1) f32, W0:(H,) f32
constexpr int B = 16;
constexpr int G = 1708;
constexpr int H = 5;
constexpr int M1 = 13;          // moments m = 0..12 (degree-12 truncation of exp series)
constexpr int JS = 4;           // j-slices per (b,h) for the moments role
constexpr int JPS = G / JS;     // 427 (1708 = 4*427 exact)
constexpr int TPB = 256;
constexpr int NMOM  = B * H * JS;            // 320 producer blocks
constexpr int EVB   = (G + TPB - 1) / TPB;   // 7 eval blocks per batch
constexpr int NEVAL = B * EVB;               // 112 consumer blocks
// Sentinel with UNEQUAL bytes: cannot collide with any byte-uniform poison fill.
#define SENT 0x1ACEB00Cu

#define LOG2E 1.4426950408889634f

// Rank-1 score structure: scores[b,i,j] = q_i * k_j, so
//   D(q) = sum_j exp(q k_j)      = sum_m (S_m/m!) q^m,  S_m = sum_j k_j^m
//   N(q) = sum_j v_j exp(q k_j)  = sum_m (T_m/m!) q^m,  T_m = sum_j v_j k_j^m
// out[b,i] = sum_h W0[h] * (N(q_i) - exp(q_i k_i) v_i) / D(q_i)
//
// SINGLE-DISPATCH producer/consumer fusion (R2 -> R3): same work split as the
// 2-kernel version (NOT the failed R5/R7 fusion where every block recomputed
// all moments). 320 moments blocks publish per-slice partials + a release flag;
// 112 eval blocks PREFETCH their global operands into registers, then
// acquire-spin on the 20 flags of their batch. Deadlock-free by counting:
// only 112 blocks spin, >=256 blocks are resident (1/CU min), so >=144
// producers always run and retire regardless of dispatch order.
//
// g_mom layout: [(b,h)][column][slice]; column 0..25 (13 D then 13 N moments),
// slice partials contiguous -> one float4 folds them. flags[] after g_mom.

__device__ __forceinline__ float fast_exp(float x) {
#if __has_builtin(__builtin_amdgcn_exp2f)
    return __builtin_amdgcn_exp2f(x * LOG2E);
#else
    return __expf(x);
#endif
}

__device__ __forceinline__ float fast_rcp(float x) {
#if __has_builtin(__builtin_amdgcn_rcpf)
    return __builtin_amdgcn_rcpf(x);   // v_rcp_f32, ~1 ulp: fine at 1e-5 abs tol
#else
    return 1.0f / x;
#endif
}

__constant__ float INVFACT[M1] = {
    (float)(1.0),                    (float)(1.0),
    (float)(1.0 / 2.0),              (float)(1.0 / 6.0),
    (float)(1.0 / 24.0),             (float)(1.0 / 120.0),
    (float)(1.0 / 720.0),            (float)(1.0 / 5040.0),
    (float)(1.0 / 40320.0),          (float)(1.0 / 362880.0),
    (float)(1.0 / 3628800.0),        (float)(1.0 / 39916800.0),
    (float)(1.0 / 479001600.0)
};

__global__ __launch_bounds__(TPB, 2)
void fused_kernel(const float* __restrict__ x,
                  const float* __restrict__ WQ,
                  const float* __restrict__ WK,
                  const float* __restrict__ WV,
                  const float* __restrict__ W0,
                  float* __restrict__ g_mom,
                  unsigned* __restrict__ flags,
                  float* __restrict__ out)
{
    __shared__ float red[4 * 8][2 * M1];          // 3.25 KB (moments role)
    __shared__ __align__(16) float mom[H * 32];   // 640 B   (eval role)

    const int tid = threadIdx.x;

    if (blockIdx.x < NMOM) {
        // ------------------------- moments role -------------------------
        const int mblk  = blockIdx.x;
        const int slice = mblk % JS;
        const int h     = (mblk / JS) % H;
        const int b     = mblk / (JS * H);
        const int j0    = slice * JPS;

        const float* __restrict__ xb = x  + b * G;
        const float* __restrict__ wk = WK + h * G;
        const float* __restrict__ wv = WV + h * G;

        float S[M1], T[M1];
#pragma unroll
        for (int m = 0; m < M1; ++m) { S[m] = 0.f; T[m] = 0.f; }

        // <=2 j's per thread; 4 parallel power chains (step k^4) keep the dep
        // chain ~3 muls deep instead of 12.
        for (int t = tid; t < JPS; t += TPB) {
            const int j    = j0 + t;
            const float xj = xb[j];
            const float k  = xj * wk[j];
            const float v  = xj * wv[j];
            const float k2 = k * k;
            const float k4 = k2 * k2;
            float p0 = 1.f, p1 = k, p2 = k2, p3 = k2 * k;
#pragma unroll
            for (int gblk = 0; gblk < 3; ++gblk) {
                const int base = gblk * 4;
                S[base + 0] += p0; T[base + 0] = fmaf(v, p0, T[base + 0]); p0 *= k4;
                S[base + 1] += p1; T[base + 1] = fmaf(v, p1, T[base + 1]); p1 *= k4;
                S[base + 2] += p2; T[base + 2] = fmaf(v, p2, T[base + 2]); p2 *= k4;
                S[base + 3] += p3; T[base + 3] = fmaf(v, p3, T[base + 3]); p3 *= k4;
            }
            S[12] += p0; T[12] = fmaf(v, p0, T[12]);   // p0 is now k^12
        }

        // 3-step butterfly: lane l ends with the sum over lanes j, j&7 == l&7.
#pragma unroll
        for (int m = 0; m < M1; ++m) {
#pragma unroll
            for (int off = 8; off <= 32; off <<= 1) {
                S[m] += __shfl_xor(S[m], off, 64);
                T[m] += __shfl_xor(T[m], off, 64);
            }
        }

        const int wave = tid >> 6;
        const int lane = tid & 63;
        if (lane < 8) {
            const int row = wave * 8 + lane;
#pragma unroll
            for (int m = 0; m < M1; ++m) {
                red[row][m]      = S[m];
                red[row][M1 + m] = T[m];
            }
        }
        __syncthreads();

        if (tid < 2 * M1) {
            const int m = tid % M1;
            float s0 = 0.f, s1 = 0.f, s2 = 0.f, s3 = 0.f;
#pragma unroll
            for (int r = 0; r < 32; r += 4) {
                s0 += red[r + 0][tid];
                s1 += red[r + 1][tid];
                s2 += red[r + 2][tid];
                s3 += red[r + 3][tid];
            }
            const float s = ((s0 + s1) + (s2 + s3)) * INVFACT[m];
            // [(b,h)][column][slice]: slice partials contiguous for the folder
            g_mom[((b * H + h) * (2 * M1) + tid) * JS + slice] = s;
        }
        // Publish. tid 0..25 all belong to wave 0, so lane 0's AGENT-release
        // store (s_waitcnt vmcnt(0) + L2 writeback) orders after the whole
        // wave's g_mom stores — no extra __syncthreads needed.
        if (tid == 0) {
            __hip_atomic_store(&flags[mblk], SENT, __ATOMIC_RELEASE,
                               __HIP_MEMORY_SCOPE_AGENT);
        }
    } else {
        // -------------------------- eval role ---------------------------
        const int e   = blockIdx.x - NMOM;
        const int b   = e / EVB;
        const int blk = e % EVB;
        const int i   = blk * TPB + tid;
        const bool act = i < G;

        // Prefetch all global operands into registers BEFORE waiting: their
        // cold-HBM latency overlaps the producers' execution.
        float xi = 0.f, wq[H], wk[H], wv[H];
        if (act) {
            xi = x[b * G + i];
#pragma unroll
            for (int h = 0; h < H; ++h) {
                wq[h] = WQ[h * G + i];
                wk[h] = WK[h * G + i];
                wv[h] = WV[h * G + i];
            }
        }
        float w0r[H];
#pragma unroll
        for (int h = 0; h < H; ++h) w0r[h] = W0[h];

        // Wait for the 20 producers of this batch (threads 0..19 in parallel).
        if (tid < H * JS) {
            const unsigned* f = &flags[b * (H * JS) + tid];
            while (__hip_atomic_load(f, __ATOMIC_ACQUIRE,
                                     __HIP_MEMORY_SCOPE_AGENT) != SENT) {
                __builtin_amdgcn_s_sleep(2);   // throttle L2-invalidate traffic
            }
        }
        __syncthreads();

        // Fold the 4 slice partials of each column: one float4 per column.
        const float4* __restrict__ gm4 =
            (const float4*)g_mom + b * (H * 2 * M1);
        for (int c = tid; c < H * 32; c += TPB) {
            const int h = c >> 5;
            const int s = c & 31;
            float val = 0.f;
            if (s < M1 || (s >= 16 && s < 16 + M1)) {
                const int cc = (s < 16) ? s : (s - 3);    // column in [0,26)
                const float4 p = gm4[h * (2 * M1) + cc];
                val = (p.x + p.y) + (p.z + p.w);
            }
            mom[c] = val;
        }
        __syncthreads();

        if (!act) return;

        float acc = 0.f;
#pragma unroll
        for (int h = 0; h < H; ++h) {
            const float q = xi * wq[h];

            // bulk LDS -> registers: 8x ds_read_b128, Horner fully in-register
            float Dm[16], Nm[16];
#pragma unroll
            for (int r = 0; r < 4; ++r) {
                *(float4*)&Dm[4 * r] = *(const float4*)&mom[h * 32 + 4 * r];
                *(float4*)&Nm[4 * r] = *(const float4*)&mom[h * 32 + 16 + 4 * r];
            }

            float D = Dm[M1 - 1];
            float N = Nm[M1 - 1];
#pragma unroll
            for (int m = M1 - 2; m >= 0; --m) {
                D = fmaf(D, q, Dm[m]);
                N = fmaf(N, q, Nm[m]);
            }

            const float k   = xi * wk[h];
            const float v   = xi * wv[h];
            const float eii = fast_exp(q * k);   // diagonal removed post-softmax
            acc = fmaf(w0r[h], (N - eii * v) * fast_rcp(D), acc);
        }
        out[b * G + i] = acc;
    }
}

extern "C" void kernel_launch(void* const* d_in, const int* in_sizes, int n_in,
                              void* d_out, int out_size, void* d_ws, size_t ws_size,
                              hipStream_t stream) {
    const float* x  = (const float*)d_in[0];
    const float* WQ = (const float*)d_in[1];
    const float* WK = (const float*)d_in[2];
    const float* WV = (const float*)d_in[3];
    const float* W0 = (const float*)d_in[4];
    float* out   = (float*)d_out;
    float* g_mom = (float*)d_ws;                        // B*H*2*M1*JS = 8320 f32
    unsigned* flags = (unsigned*)(g_mom + B * H * 2 * M1 * JS);  // 320 u32

    fused_kernel<<<NMOM + NEVAL, TPB, 0, stream>>>(x, WQ, WK, WV, W0,
                                                   g_mom, flags, out);
}

// Round 4
// 67.056 us; speedup vs baseline: 1.0520x; 1.0520x over previous
//
#include <hip/hip_runtime.h>

// Problem constants: x:(B,G) f32, WQ/WK/WV:(H,G,1) f32, W0:(H,) f32
constexpr int B = 16;
constexpr int G = 1708;
constexpr int H = 5;
constexpr int M1 = 13;          // moments m = 0..12 (degree-12 truncation of exp series)
constexpr int TPB  = 640;       // 10 waves = 2 waves (128 threads) per head
constexpr int RB   = 7;         // blocks per batch; 7 * 244 = 1708 exact
constexpr int ROWS = G / RB;    // 244 eval rows per block
constexpr int NBLK = B * RB;    // 112 blocks

#define LOG2E 1.4426950408889634f

// Rank-1 score structure: scores[b,i,j] = q_i * k_j, so
//   D(q) = sum_j exp(q k_j)      = sum_m (S_m/m!) q^m,  S_m = sum_j k_j^m
//   N(q) = sum_j v_j exp(q k_j)  = sum_m (T_m/m!) q^m,  T_m = sum_j v_j k_j^m
// out[b,i] = sum_h W0[h] * (N(q_i) - exp(q_i k_i) v_i) / D(q_i)
// |q k| <= ~1.4 => degree-12 tail < 1.4^13/13! ~ 1.3e-8: invisible at fp32 tol.
//
// SINGLE NODE, ZERO CROSS-BLOCK DEPS (R3 post-mortem: agent-scope
// release/acquire spin cost more than the dispatch gap it removed — L2
// writeback/invalidate storm). Here each block is self-sufficient:
//   phase 1: all 5 heads' moments for its batch b (2 waves per head ->
//            per-thread state = ONE head's 26 accumulators, chain depth 14;
//            NOT the failed R5/R7 fusion whose threads held deep serial
//            chains with every head's accumulators live)
//   phase 2: LDS fold (16 partial rows per head) + 1/m! scaling
//   phase 3: eval 244 rows (Horner deg-12, per-head fix for the diagonal)
// Moments are 7x redundant across the rb-blocks of a batch: redundant FLOPs
// run on otherwise-idle CUs (wall time unchanged); the XCD-chunked block
// mapping parks all 7 blocks of a batch on ONE XCD so they share L2 lines.
// Eval operands are prefetched into registers at kernel entry: their cold-HBM
// latency overlaps phase 1.

__device__ __forceinline__ float fast_exp(float x) {
#if __has_builtin(__builtin_amdgcn_exp2f)
    return __builtin_amdgcn_exp2f(x * LOG2E);
#else
    return __expf(x);
#endif
}

__device__ __forceinline__ float fast_rcp(float x) {
#if __has_builtin(__builtin_amdgcn_rcpf)
    return __builtin_amdgcn_rcpf(x);   // v_rcp_f32, ~1 ulp: fine at 1e-5 abs tol
#else
    return 1.0f / x;
#endif
}

__constant__ float INVFACT[M1] = {
    (float)(1.0),                    (float)(1.0),
    (float)(1.0 / 2.0),              (float)(1.0 / 6.0),
    (float)(1.0 / 24.0),             (float)(1.0 / 120.0),
    (float)(1.0 / 720.0),            (float)(1.0 / 5040.0),
    (float)(1.0 / 40320.0),          (float)(1.0 / 362880.0),
    (float)(1.0 / 3628800.0),        (float)(1.0 / 39916800.0),
    (float)(1.0 / 479001600.0)
};

__global__ __launch_bounds__(TPB, 1)
void fused_kernel(const float* __restrict__ x,
                  const float* __restrict__ WQ,
                  const float* __restrict__ WK,
                  const float* __restrict__ WV,
                  const float* __restrict__ W0,
                  float* __restrict__ out)
{
    __shared__ float red[10 * 8][2 * M1];         // 80 rows x 26 = 8.3 KB
    __shared__ __align__(16) float mom[H * 32];   // padded D/N halves, 640 B

    // XCD-chunked mapping: dispatch d lands on XCD d%8 (default round-robin);
    // give XCD x the two batches {2x, 2x+1} -> all 7 blocks of a batch share
    // one XCD's L2 (their loads of x_b/WK/WV are the same lines).
    const int d    = blockIdx.x;
    const int xcd  = d & 7;
    const int slot = d >> 3;               // 0..13
    const int b    = 2 * xcd + (slot >= RB ? 1 : 0);
    const int rb   = (slot >= RB) ? slot - RB : slot;

    const int tid = threadIdx.x;

    // ---- prefetch eval operands into registers (latency hides under phase 1)
    const int  i   = rb * ROWS + tid;      // this thread's output row
    const bool act = tid < ROWS;
    float xi = 0.f, wq[H], wk[H], wv[H];
    if (act) {
        xi = x[b * G + i];
#pragma unroll
        for (int h = 0; h < H; ++h) {
            wq[h] = WQ[h * G + i];
            wk[h] = WK[h * G + i];
            wv[h] = WV[h * G + i];
        }
    }
    float w0r[H];
#pragma unroll
    for (int h = 0; h < H; ++h) w0r[h] = W0[h];

    // ---- phase 1: moments for head tid/128 over j = (tid%128) + 128*it ----
    {
        const int hM = tid >> 7;           // 0..4
        const int g  = tid & 127;

        const float* __restrict__ xb  = x  + b * G;
        const float* __restrict__ wkp = WK + hM * G;
        const float* __restrict__ wvp = WV + hM * G;

        float S[M1], T[M1];
#pragma unroll
        for (int m = 0; m < M1; ++m) { S[m] = 0.f; T[m] = 0.f; }

        for (int j = g; j < G; j += 128) {
            const float xj = xb[j];
            const float k  = xj * wkp[j];
            const float v  = xj * wvp[j];
            const float k2 = k * k;
            const float k4 = k2 * k2;
            float p0 = 1.f, p1 = k, p2 = k2, p3 = k2 * k;
#pragma unroll
            for (int gblk = 0; gblk < 3; ++gblk) {
                const int base = gblk * 4;
                S[base + 0] += p0; T[base + 0] = fmaf(v, p0, T[base + 0]); p0 *= k4;
                S[base + 1] += p1; T[base + 1] = fmaf(v, p1, T[base + 1]); p1 *= k4;
                S[base + 2] += p2; T[base + 2] = fmaf(v, p2, T[base + 2]); p2 *= k4;
                S[base + 3] += p3; T[base + 3] = fmaf(v, p3, T[base + 3]); p3 *= k4;
            }
            S[12] += p0; T[12] = fmaf(v, p0, T[12]);   // p0 is now k^12
        }

        // 3-step butterfly: lane l ends with the sum over lanes l' = l (mod 8)
#pragma unroll
        for (int m = 0; m < M1; ++m) {
#pragma unroll
            for (int off = 8; off <= 32; off <<= 1) {
                S[m] += __shfl_xor(S[m], off, 64);
                T[m] += __shfl_xor(T[m], off, 64);
            }
        }

        const int wave = tid >> 6;         // 0..9; head hM owns waves 2hM,2hM+1
        const int lane = tid & 63;
        if (lane < 8) {
            const int row = wave * 8 + lane;
#pragma unroll
            for (int m = 0; m < M1; ++m) {
                red[row][m]      = S[m];
                red[row][M1 + m] = T[m];
            }
        }
    }
    __syncthreads();

    // ---- phase 2: fold 16 partial rows per head, scale by 1/m!, park in mom
    if (tid < H * 32) {
        const int h = tid >> 5;
        const int s = tid & 31;
        float val = 0.f;
        if (s < M1 || (s >= 16 && s < 16 + M1)) {
            const int c = (s < 16) ? s : (s - 3);   // column 0..25 (13 D, 13 N)
            float s0 = 0.f, s1 = 0.f, s2 = 0.f, s3 = 0.f;
#pragma unroll
            for (int r = 0; r < 16; r += 4) {
                s0 += red[16 * h + r + 0][c];
                s1 += red[16 * h + r + 1][c];
                s2 += red[16 * h + r + 2][c];
                s3 += red[16 * h + r + 3][c];
            }
            val = ((s0 + s1) + (s2 + s3)) * INVFACT[c % M1];
        }
        mom[tid] = val;   // tid == h*32 + s
    }
    __syncthreads();

    // ---- phase 3: eval this thread's row ----
    if (!act) return;

    float acc = 0.f;
#pragma unroll
    for (int h = 0; h < H; ++h) {
        const float q = xi * wq[h];

        // bulk LDS -> registers: 8x ds_read_b128, Horner fully in-register
        float Dm[16], Nm[16];
#pragma unroll
        for (int r = 0; r < 4; ++r) {
            *(float4*)&Dm[4 * r] = *(const float4*)&mom[h * 32 + 4 * r];
            *(float4*)&Nm[4 * r] = *(const float4*)&mom[h * 32 + 16 + 4 * r];
        }

        float D = Dm[M1 - 1];
        float N = Nm[M1 - 1];
#pragma unroll
        for (int m = M1 - 2; m >= 0; --m) {
            D = fmaf(D, q, Dm[m]);
            N = fmaf(N, q, Nm[m]);
        }

        const float k   = xi * wk[h];
        const float v   = xi * wv[h];
        const float eii = fast_exp(q * k);   // diagonal removed post-softmax
        acc = fmaf(w0r[h], (N - eii * v) * fast_rcp(D), acc);
    }
    out[b * G + i] = acc;
}

extern "C" void kernel_launch(void* const* d_in, const int* in_sizes, int n_in,
                              void* d_out, int out_size, void* d_ws, size_t ws_size,
                              hipStream_t stream) {
    const float* x  = (const float*)d_in[0];
    const float* WQ = (const float*)d_in[1];
    const float* WK = (const float*)d_in[2];
    const float* WV = (const float*)d_in[3];
    const float* W0 = (const float*)d_in[4];
    float* out = (float*)d_out;
    (void)d_ws; (void)ws_size;   // no workspace: moments stay on-chip

    fused_kernel<<<NBLK, TPB, 0, stream>>>(x, WQ, WK, WV, W0, out);
}

// Round 5
// 66.282 us; speedup vs baseline: 1.0643x; 1.0117x over previous
//
#include <hip/hip_runtime.h>

// Problem constants (from reference): x:(B,G) f32, WQ/WK/WV:(H,G,1) f32, W0:(H,) f32
constexpr int B = 16;
constexpr int G = 1708;
constexpr int H = 5;
constexpr int M1 = 13;          // moments m = 0..12 (degree-12 truncation of exp series)
constexpr int JS = 4;           // j-slices per (b,h) in the moments kernel
constexpr int JPS = G / JS;     // 427 (1708 = 4*427 exact)
constexpr int TPB1 = 256;       // moments kernel block
constexpr int TPB2 = 256;       // eval kernel block (4 waves -> latency hiding)

#define LOG2E 1.4426950408889634f

// Rank-1 score structure: scores[b,i,j] = q_i * k_j, so
//   D(q) = sum_j exp(q k_j)      = sum_m (S_m/m!) q^m,  S_m = sum_j k_j^m
//   N(q) = sum_j v_j exp(q k_j)  = sum_m (T_m/m!) q^m,  T_m = sum_j v_j k_j^m
// out[b,i] = sum_h W0[h] * (N(q_i) - exp(q_i k_i) v_i) / D(q_i)
// |q k| <= ~1.4  =>  degree-12 tail < 1.4^13/13! ~ 1.3e-8 per element: far below
// the fp32 tolerance.
//
// STRUCTURE LEDGER (this session): two-node M1=13 = 66.31 us (best);
// fused-by-spin (agent fences) = 70.54; fused self-sufficient = 67.06;
// => inter-node gap is <~1 us, fusion buys nothing; cross-block fences are
// actively harmful (L2 writeback/invalidate storm). This file restores the
// measured-best R2 variant.
//
// g_mom layout: [(b,h)][column][slice], column = 0..25 (13 D-moments then 13
// N-moments), slice = 0..3. Slice partials contiguous -> eval folds each
// column with one float4 load. Disjoint writes: no atomics, no memset node.

__device__ __forceinline__ float fast_exp(float x) {
#if __has_builtin(__builtin_amdgcn_exp2f)
    return __builtin_amdgcn_exp2f(x * LOG2E);
#else
    return __expf(x);
#endif
}

__device__ __forceinline__ float fast_rcp(float x) {
#if __has_builtin(__builtin_amdgcn_rcpf)
    return __builtin_amdgcn_rcpf(x);   // v_rcp_f32, ~1 ulp: fine at 1e-5 abs tol
#else
    return 1.0f / x;
#endif
}

__constant__ float INVFACT[M1] = {
    (float)(1.0),                    (float)(1.0),
    (float)(1.0 / 2.0),              (float)(1.0 / 6.0),
    (float)(1.0 / 24.0),             (float)(1.0 / 120.0),
    (float)(1.0 / 720.0),            (float)(1.0 / 5040.0),
    (float)(1.0 / 40320.0),          (float)(1.0 / 362880.0),
    (float)(1.0 / 3628800.0),        (float)(1.0 / 39916800.0),
    (float)(1.0 / 479001600.0)
};

// Kernel 1: grid = B*H*JS blocks; block reduces one j-slice of one (b,h) and
// STORES the 26 scaled partial moments to its own g_mom slot (disjoint).
__global__ __launch_bounds__(TPB1)
void moments_kernel(const float* __restrict__ x,
                    const float* __restrict__ WK,
                    const float* __restrict__ WV,
                    float* __restrict__ g_mom)
{
    const int slice = blockIdx.x % JS;
    const int h     = (blockIdx.x / JS) % H;
    const int b     = blockIdx.x / (JS * H);
    const int j0    = slice * JPS;

    const float* __restrict__ xb = x  + b * G;
    const float* __restrict__ wk = WK + h * G;
    const float* __restrict__ wv = WV + h * G;

    float S[M1], T[M1];
#pragma unroll
    for (int m = 0; m < M1; ++m) { S[m] = 0.f; T[m] = 0.f; }

    // <=2 j's per thread; 4 parallel power chains (step k^4) keep the dep
    // chain ~3 muls deep instead of 12.
    for (int t = threadIdx.x; t < JPS; t += TPB1) {
        const int j   = j0 + t;
        const float xj = xb[j];
        const float k  = xj * wk[j];
        const float v  = xj * wv[j];
        const float k2 = k * k;
        const float k4 = k2 * k2;
        float p0 = 1.f, p1 = k, p2 = k2, p3 = k2 * k;
#pragma unroll
        for (int gblk = 0; gblk < 3; ++gblk) {
            const int base = gblk * 4;
            S[base + 0] += p0; T[base + 0] = fmaf(v, p0, T[base + 0]); p0 *= k4;
            S[base + 1] += p1; T[base + 1] = fmaf(v, p1, T[base + 1]); p1 *= k4;
            S[base + 2] += p2; T[base + 2] = fmaf(v, p2, T[base + 2]); p2 *= k4;
            S[base + 3] += p3; T[base + 3] = fmaf(v, p3, T[base + 3]); p3 *= k4;
        }
        S[12] += p0; T[12] = fmaf(v, p0, T[12]);   // p0 is now k^12
    }

    // 3-step butterfly: lane l ends with the sum over lanes j with j&7 == l&7.
#pragma unroll
    for (int m = 0; m < M1; ++m) {
#pragma unroll
        for (int off = 8; off <= 32; off <<= 1) {
            S[m] += __shfl_xor(S[m], off, 64);
            T[m] += __shfl_xor(T[m], off, 64);
        }
    }

    __shared__ float red[4 * 8][2 * M1];   // 32 rows x 26 scalars = 3.25 KB
    const int wave = threadIdx.x >> 6;
    const int lane = threadIdx.x & 63;
    if (lane < 8) {
        const int row = wave * 8 + lane;
#pragma unroll
        for (int m = 0; m < M1; ++m) {
            red[row][m]      = S[m];
            red[row][M1 + m] = T[m];
        }
    }
    __syncthreads();

    if (threadIdx.x < 2 * M1) {
        const int m = threadIdx.x % M1;
        float s0 = 0.f, s1 = 0.f, s2 = 0.f, s3 = 0.f;
#pragma unroll
        for (int r = 0; r < 32; r += 4) {
            s0 += red[r + 0][threadIdx.x];
            s1 += red[r + 1][threadIdx.x];
            s2 += red[r + 2][threadIdx.x];
            s3 += red[r + 3][threadIdx.x];
        }
        const float s = ((s0 + s1) + (s2 + s3)) * INVFACT[m];
        // transposed layout: [(b,h)][column][slice] -> slice partials contiguous
        g_mom[((b * H + h) * (2 * M1) + threadIdx.x) * JS + slice] = s;
    }
}

// Kernel 2: 4 waves per 256 rows. One float4 load folds the 4 slice partials of
// each moment column; moments parked in LDS padded to 16B-aligned D/N halves so
// the per-head pull is 8x ds_read_b128 into registers; Horner fully in-register.
__global__ __launch_bounds__(TPB2)
void eval_kernel(const float* __restrict__ x,
                 const float* __restrict__ WQ,
                 const float* __restrict__ WK,
                 const float* __restrict__ WV,
                 const float* __restrict__ W0,
                 const float* __restrict__ g_mom,
                 float* __restrict__ out)
{
    // per head 32 slots: D-moments at [0..12], N-moments at [16..28], pads 0
    __shared__ __align__(16) float mom[H * 32];   // 640 B

    const int b = blockIdx.y;
    const int i = blockIdx.x * TPB2 + threadIdx.x;

    const float4* __restrict__ gm4 =
        (const float4*)g_mom + b * (H * 2 * M1);   // float4 per column

    for (int c = threadIdx.x; c < H * 32; c += TPB2) {
        const int h = c >> 5;
        const int s = c & 31;
        float val = 0.f;
        if (s < M1 || (s >= 16 && s < 16 + M1)) {
            const int cc = (s < 16) ? s : (s - 3);        // column in [0,26)
            const float4 p = gm4[h * (2 * M1) + cc];
            val = (p.x + p.y) + (p.z + p.w);              // fold 4 slices
        }
        mom[c] = val;
    }
    __syncthreads();

    if (i >= G) return;

    const float xi = x[b * G + i];
    float acc = 0.f;

#pragma unroll
    for (int h = 0; h < H; ++h) {
        const float q = xi * WQ[h * G + i];

        // bulk LDS -> registers: 8x ds_read_b128 (vs 2*M1 scalar reads)
        float Dm[16], Nm[16];
#pragma unroll
        for (int r = 0; r < 4; ++r) {
            *(float4*)&Dm[4 * r] = *(const float4*)&mom[h * 32 + 4 * r];
            *(float4*)&Nm[4 * r] = *(const float4*)&mom[h * 32 + 16 + 4 * r];
        }

        float D = Dm[M1 - 1];
        float N = Nm[M1 - 1];
#pragma unroll
        for (int m = M1 - 2; m >= 0; --m) {
            D = fmaf(D, q, Dm[m]);
            N = fmaf(N, q, Nm[m]);
        }

        const float k   = xi * WK[h * G + i];
        const float v   = xi * WV[h * G + i];
        const float eii = fast_exp(q * k);       // diagonal removed post-softmax
        acc = fmaf(W0[h], (N - eii * v) * fast_rcp(D), acc);
    }
    out[b * G + i] = acc;
}

extern "C" void kernel_launch(void* const* d_in, const int* in_sizes, int n_in,
                              void* d_out, int out_size, void* d_ws, size_t ws_size,
                              hipStream_t stream) {
    const float* x  = (const float*)d_in[0];
    const float* WQ = (const float*)d_in[1];
    const float* WK = (const float*)d_in[2];
    const float* WV = (const float*)d_in[3];
    const float* W0 = (const float*)d_in[4];
    float* out   = (float*)d_out;
    float* g_mom = (float*)d_ws;            // B*H*2*M1*JS floats = 32.5 KB

    moments_kernel<<<B * H * JS, TPB1, 0, stream>>>(x, WK, WV, g_mom);

    dim3 grid2((G + TPB2 - 1) / TPB2, B);   // (7, 16), 4 waves per block
    eval_kernel<<<grid2, TPB2, 0, stream>>>(x, WQ, WK, WV, W0, g_mom, out);
}